// Round 1
// baseline (11097.094 us; speedup 1.0000x reference)
//
#include <hip/hip_runtime.h>

#ifndef __HIP_PLATFORM_AMD__
#define unsafeAtomicAdd atomicAdd
#endif

// ---------------------------------------------------------------------------
// GCN, 6 layers, N=1M nodes, E=16M edges.
// Layer k: h_{k+1} = relu(((A (h_k*norm))*norm) @ Wk + bk)
// Fusion: node kernels produce s = h*norm (the per-edge message) directly and
// zero the next agg buffer, so no memsets are needed.
// Layer 6 applies W6 BEFORE aggregation (linear algebra identity) so both the
// first and last edge passes scatter only 1 float/edge.
// ---------------------------------------------------------------------------

__global__ void k_init1(const float* __restrict__ feat, const float* __restrict__ norm,
                        float* __restrict__ sB, float* __restrict__ aggB, int N) {
  int i = blockIdx.x * blockDim.x + threadIdx.x;
  if (i < N) {
    sB[i] = feat[i] * norm[i];
    aggB[i] = 0.0f;
  }
}

// 1 float per edge: sB (stride 1) -> aggB (stride 1)
__global__ void k_edge1(const int* __restrict__ src, const int* __restrict__ dst,
                        const float* __restrict__ s, float* __restrict__ agg, int E) {
  int t = blockIdx.x * blockDim.x + threadIdx.x;
  int base = t * 4;
  if (base + 3 < E) {
    int4 u = *(const int4*)(src + base);
    int4 v = *(const int4*)(dst + base);
    float x0 = s[u.x], x1 = s[u.y], x2 = s[u.z], x3 = s[u.w];
    unsafeAtomicAdd(&agg[v.x], x0);
    unsafeAtomicAdd(&agg[v.y], x1);
    unsafeAtomicAdd(&agg[v.z], x2);
    unsafeAtomicAdd(&agg[v.w], x3);
  } else if (base < E) {
    for (int k = base; k < E; ++k) unsafeAtomicAdd(&agg[dst[k]], s[src[k]]);
  }
}

// 3 floats per edge: sA (stride 4, padded) -> aggA (stride 4)
__global__ void k_edge3(const int* __restrict__ src, const int* __restrict__ dst,
                        const float* __restrict__ s, float* __restrict__ agg, int E) {
  int t = blockIdx.x * blockDim.x + threadIdx.x;
  int base = t * 4;
  if (base + 3 < E) {
    int4 u = *(const int4*)(src + base);
    int4 v = *(const int4*)(dst + base);
    float4 a = ((const float4*)s)[u.x];
    float4 b = ((const float4*)s)[u.y];
    float4 c = ((const float4*)s)[u.z];
    float4 d = ((const float4*)s)[u.w];
    unsafeAtomicAdd(&agg[(size_t)v.x * 4 + 0], a.x);
    unsafeAtomicAdd(&agg[(size_t)v.x * 4 + 1], a.y);
    unsafeAtomicAdd(&agg[(size_t)v.x * 4 + 2], a.z);
    unsafeAtomicAdd(&agg[(size_t)v.y * 4 + 0], b.x);
    unsafeAtomicAdd(&agg[(size_t)v.y * 4 + 1], b.y);
    unsafeAtomicAdd(&agg[(size_t)v.y * 4 + 2], b.z);
    unsafeAtomicAdd(&agg[(size_t)v.z * 4 + 0], c.x);
    unsafeAtomicAdd(&agg[(size_t)v.z * 4 + 1], c.y);
    unsafeAtomicAdd(&agg[(size_t)v.z * 4 + 2], c.z);
    unsafeAtomicAdd(&agg[(size_t)v.w * 4 + 0], d.x);
    unsafeAtomicAdd(&agg[(size_t)v.w * 4 + 1], d.y);
    unsafeAtomicAdd(&agg[(size_t)v.w * 4 + 2], d.z);
  } else if (base < E) {
    for (int k = base; k < E; ++k) {
      int u = src[k], v = dst[k];
      unsafeAtomicAdd(&agg[(size_t)v * 4 + 0], s[(size_t)u * 4 + 0]);
      unsafeAtomicAdd(&agg[(size_t)v * 4 + 1], s[(size_t)u * 4 + 1]);
      unsafeAtomicAdd(&agg[(size_t)v * 4 + 2], s[(size_t)u * 4 + 2]);
    }
  }
}

// After layer-1 edge pass: h2 = relu((aggB*norm) @ W1 + b1)  (W1 is 1x3)
// Emit s2 = h2*norm (stride 4) and zero aggA.
__global__ void k_node12(const float* __restrict__ norm, const float* __restrict__ W1,
                         const float* __restrict__ b1, const float* __restrict__ aggB,
                         float* __restrict__ sA, float* __restrict__ aggA, int N) {
  int i = blockIdx.x * blockDim.x + threadIdx.x;
  if (i >= N) return;
  float n = norm[i];
  float pre = aggB[i] * n;
  float h0 = fmaxf(0.0f, pre * W1[0] + b1[0]);
  float h1 = fmaxf(0.0f, pre * W1[1] + b1[1]);
  float h2 = fmaxf(0.0f, pre * W1[2] + b1[2]);
  ((float4*)sA)[i] = make_float4(h0 * n, h1 * n, h2 * n, 0.0f);
  ((float4*)aggA)[i] = make_float4(0.0f, 0.0f, 0.0f, 0.0f);
}

// Generic 3->3 layer: h' = relu((aggA*norm) @ W + b); emit s' = h'*norm; zero aggA.
// Same-index read/write on aggA => no cross-thread race.
__global__ void k_node33(const float* __restrict__ norm, const float* __restrict__ W,
                         const float* __restrict__ b, float* __restrict__ sA,
                         float* __restrict__ aggA, int N) {
  int i = blockIdx.x * blockDim.x + threadIdx.x;
  if (i >= N) return;
  float n = norm[i];
  float4 ag = ((const float4*)aggA)[i];
  float a0 = ag.x * n, a1 = ag.y * n, a2 = ag.z * n;
  float h0 = fmaxf(0.0f, a0 * W[0] + a1 * W[3] + a2 * W[6] + b[0]);
  float h1 = fmaxf(0.0f, a0 * W[1] + a1 * W[4] + a2 * W[7] + b[1]);
  float h2 = fmaxf(0.0f, a0 * W[2] + a1 * W[5] + a2 * W[8] + b[2]);
  ((float4*)sA)[i] = make_float4(h0 * n, h1 * n, h2 * n, 0.0f);
  ((float4*)aggA)[i] = make_float4(0.0f, 0.0f, 0.0f, 0.0f);
}

// After layer-5 edge pass: h6 = relu((aggA*norm) @ W5 + b5), then transform-first
// for layer 6: sB = (h6 @ W6) * norm (W6 is 3x1). Zero aggB.
__global__ void k_node56(const float* __restrict__ norm, const float* __restrict__ W5,
                         const float* __restrict__ b5, const float* __restrict__ W6,
                         const float* __restrict__ aggA, float* __restrict__ sB,
                         float* __restrict__ aggB, int N) {
  int i = blockIdx.x * blockDim.x + threadIdx.x;
  if (i >= N) return;
  float n = norm[i];
  float4 ag = ((const float4*)aggA)[i];
  float a0 = ag.x * n, a1 = ag.y * n, a2 = ag.z * n;
  float h0 = fmaxf(0.0f, a0 * W5[0] + a1 * W5[3] + a2 * W5[6] + b5[0]);
  float h1 = fmaxf(0.0f, a0 * W5[1] + a1 * W5[4] + a2 * W5[7] + b5[1]);
  float h2 = fmaxf(0.0f, a0 * W5[2] + a1 * W5[5] + a2 * W5[8] + b5[2]);
  float g = (h0 * W6[0] + h1 * W6[1] + h2 * W6[2]) * n;
  sB[i] = g;
  aggB[i] = 0.0f;
}

// out = relu(aggB*norm + b6)
__global__ void k_final(const float* __restrict__ norm, const float* __restrict__ b6,
                        const float* __restrict__ aggB, float* __restrict__ out, int N) {
  int i = blockIdx.x * blockDim.x + threadIdx.x;
  if (i >= N) return;
  out[i] = fmaxf(0.0f, aggB[i] * norm[i] + b6[0]);
}

extern "C" void kernel_launch(void* const* d_in, const int* in_sizes, int n_in,
                              void* d_out, int out_size, void* d_ws, size_t ws_size,
                              hipStream_t stream) {
  const float* feat = (const float*)d_in[0];
  const float* norm = (const float*)d_in[1];
  const int* src = (const int*)d_in[2];
  const int* dst = (const int*)d_in[3];
  const float* W1 = (const float*)d_in[4];
  const float* b1 = (const float*)d_in[5];
  const float* W2 = (const float*)d_in[6];
  const float* b2 = (const float*)d_in[7];
  const float* W3 = (const float*)d_in[8];
  const float* b3 = (const float*)d_in[9];
  const float* W4 = (const float*)d_in[10];
  const float* b4 = (const float*)d_in[11];
  const float* W5 = (const float*)d_in[12];
  const float* b5 = (const float*)d_in[13];
  const float* W6 = (const float*)d_in[14];
  const float* b6 = (const float*)d_in[15];
  float* out = (float*)d_out;

  const int N = in_sizes[0];
  const int E = in_sizes[2];

  // Workspace layout (floats): sA[4N] | aggA[4N] | sB[N] | aggB[N]  = 40 MB
  float* sA = (float*)d_ws;
  float* aggA = sA + (size_t)4 * N;
  float* sB = aggA + (size_t)4 * N;
  float* aggB = sB + (size_t)N;

  const int BT = 256;
  const int nbNode = (N + BT - 1) / BT;
  const int nbEdge = ((E + 3) / 4 + BT - 1) / BT;

  // Layer 1 (1->3): aggregate scalar, then transform.
  k_init1<<<nbNode, BT, 0, stream>>>(feat, norm, sB, aggB, N);
  k_edge1<<<nbEdge, BT, 0, stream>>>(src, dst, sB, aggB, E);
  k_node12<<<nbNode, BT, 0, stream>>>(norm, W1, b1, aggB, sA, aggA, N);

  // Layer 2 (3->3)
  k_edge3<<<nbEdge, BT, 0, stream>>>(src, dst, sA, aggA, E);
  k_node33<<<nbNode, BT, 0, stream>>>(norm, W2, b2, sA, aggA, N);

  // Layer 3 (3->3)
  k_edge3<<<nbEdge, BT, 0, stream>>>(src, dst, sA, aggA, E);
  k_node33<<<nbNode, BT, 0, stream>>>(norm, W3, b3, sA, aggA, N);

  // Layer 4 (3->3)
  k_edge3<<<nbEdge, BT, 0, stream>>>(src, dst, sA, aggA, E);
  k_node33<<<nbNode, BT, 0, stream>>>(norm, W4, b4, sA, aggA, N);

  // Layer 5 (3->3) edge pass, then fused layer-5 transform + layer-6 pre-transform
  k_edge3<<<nbEdge, BT, 0, stream>>>(src, dst, sA, aggA, E);
  k_node56<<<nbNode, BT, 0, stream>>>(norm, W5, b5, W6, aggA, sB, aggB, N);

  // Layer 6 (3->1): aggregate scalar (W6 already applied), then finish.
  k_edge1<<<nbEdge, BT, 0, stream>>>(src, dst, sB, aggB, E);
  k_final<<<nbNode, BT, 0, stream>>>(norm, b6, aggB, out, N);
}

// Round 2
// 3714.302 us; speedup vs baseline: 2.9877x; 2.9877x over previous
//
#include <hip/hip_runtime.h>

// ---------------------------------------------------------------------------
// GCN, 6 layers, N=1M nodes, E=16M edges.
// R2 strategy: counting-sort edges by dst into CSR once per launch (paid once),
// then each layer is a single fused kernel: segmented sum over in-edges
// (no atomics) + norm * GEMV * ReLU + pre-scale for the next layer's messages.
// Layer 6 applies W6 before aggregation (right-mult by W commutes with A).
// ---------------------------------------------------------------------------

#define BT 256

// s0 = feat * norm
__global__ void k_init(const float* __restrict__ feat, const float* __restrict__ norm,
                       float* __restrict__ s0, int N) {
  int i = blockIdx.x * BT + threadIdx.x;
  if (i < N) s0[i] = feat[i] * norm[i];
}

__global__ void k_zero(int* __restrict__ p, int n) {
  int i = blockIdx.x * BT + threadIdx.x;
  if (i < n) p[i] = 0;
}

// histogram of dst
__global__ void k_hist(const int* __restrict__ dst, int* __restrict__ count, int E) {
  int t = blockIdx.x * BT + threadIdx.x;
  int base = t * 4;
  if (base + 3 < E) {
    int4 v = *(const int4*)(dst + base);
    atomicAdd(&count[v.x], 1);
    atomicAdd(&count[v.y], 1);
    atomicAdd(&count[v.z], 1);
    atomicAdd(&count[v.w], 1);
  } else if (base < E) {
    for (int k = base; k < E; ++k) atomicAdd(&count[dst[k]], 1);
  }
}

// scan phase A: per-block sums
__global__ void k_blockSum(const int* __restrict__ count, int* __restrict__ partial, int N) {
  __shared__ int tmp[BT];
  int i = blockIdx.x * BT + threadIdx.x;
  int v = (i < N) ? count[i] : 0;
  tmp[threadIdx.x] = v;
  __syncthreads();
  for (int off = BT / 2; off > 0; off >>= 1) {
    if (threadIdx.x < off) tmp[threadIdx.x] += tmp[threadIdx.x + off];
    __syncthreads();
  }
  if (threadIdx.x == 0) partial[blockIdx.x] = tmp[0];
}

// scan phase B: exclusive scan of partials, single block
__global__ void k_scanPartials(int* __restrict__ partial, int nb) {
  __shared__ int tmp[BT];
  __shared__ int carry;
  int t = threadIdx.x;
  if (t == 0) carry = 0;
  __syncthreads();
  for (int base = 0; base < nb; base += BT) {
    int i = base + t;
    int v = (i < nb) ? partial[i] : 0;
    tmp[t] = v;
    __syncthreads();
    for (int off = 1; off < BT; off <<= 1) {
      int x = 0;
      if (t >= off) x = tmp[t - off];
      __syncthreads();
      tmp[t] += x;
      __syncthreads();
    }
    if (i < nb) partial[i] = tmp[t] - v + carry;  // exclusive + carry
    __syncthreads();
    if (t == BT - 1) carry += tmp[BT - 1];
    __syncthreads();
  }
}

// scan phase C: final exclusive scan -> row_ptr, cursor
__global__ void k_scanFinal(const int* __restrict__ count, const int* __restrict__ partial,
                            int* __restrict__ row_ptr, int* __restrict__ cursor, int N, int E) {
  __shared__ int tmp[BT];
  int t = threadIdx.x;
  int i = blockIdx.x * BT + t;
  int v = (i < N) ? count[i] : 0;
  tmp[t] = v;
  __syncthreads();
  for (int off = 1; off < BT; off <<= 1) {
    int x = 0;
    if (t >= off) x = tmp[t - off];
    __syncthreads();
    tmp[t] += x;
    __syncthreads();
  }
  int excl = tmp[t] - v + partial[blockIdx.x];
  if (i < N) {
    row_ptr[i] = excl;
    cursor[i] = excl;
  }
  if (i == N - 1) row_ptr[N] = excl + v;  // == E
}

// scatter: perm[pos] = src, bucketed by dst
__global__ void k_scatter(const int* __restrict__ src, const int* __restrict__ dst,
                          int* __restrict__ cursor, int* __restrict__ perm, int E) {
  int t = blockIdx.x * BT + threadIdx.x;
  int base = t * 4;
  if (base + 3 < E) {
    int4 u = *(const int4*)(src + base);
    int4 v = *(const int4*)(dst + base);
    perm[atomicAdd(&cursor[v.x], 1)] = u.x;
    perm[atomicAdd(&cursor[v.y], 1)] = u.y;
    perm[atomicAdd(&cursor[v.z], 1)] = u.z;
    perm[atomicAdd(&cursor[v.w], 1)] = u.w;
  } else if (base < E) {
    for (int k = base; k < E; ++k) perm[atomicAdd(&cursor[dst[k]], 1)] = src[k];
  }
}

// Layer 1 (1->3): t = sum s0[perm]; pre = t*n; h = relu(pre*W1+b1); sA = h*n
__global__ void k_aggL1(const int* __restrict__ row_ptr, const int* __restrict__ perm,
                        const float* __restrict__ s0, const float* __restrict__ norm,
                        const float* __restrict__ W1, const float* __restrict__ b1,
                        float* __restrict__ sA, int N) {
  int i = blockIdx.x * BT + threadIdx.x;
  if (i >= N) return;
  int beg = row_ptr[i], end = row_ptr[i + 1];
  float t = 0.0f;
  for (int e = beg; e < end; ++e) t += s0[perm[e]];
  float n = norm[i];
  float pre = t * n;
  float h0 = fmaxf(0.0f, pre * W1[0] + b1[0]);
  float h1 = fmaxf(0.0f, pre * W1[1] + b1[1]);
  float h2 = fmaxf(0.0f, pre * W1[2] + b1[2]);
  ((float4*)sA)[i] = make_float4(h0 * n, h1 * n, h2 * n, 0.0f);
}

// Layers 2-4 (3->3): segmented float4 sum + GEMV + relu + pre-scale
__global__ void k_agg3(const int* __restrict__ row_ptr, const int* __restrict__ perm,
                       const float* __restrict__ sPrev, const float* __restrict__ norm,
                       const float* __restrict__ W, const float* __restrict__ b,
                       float* __restrict__ sNext, int N) {
  int i = blockIdx.x * BT + threadIdx.x;
  if (i >= N) return;
  int beg = row_ptr[i], end = row_ptr[i + 1];
  float a0 = 0.0f, a1 = 0.0f, a2 = 0.0f;
  for (int e = beg; e < end; ++e) {
    float4 m = ((const float4*)sPrev)[perm[e]];
    a0 += m.x;
    a1 += m.y;
    a2 += m.z;
  }
  float n = norm[i];
  a0 *= n; a1 *= n; a2 *= n;
  float h0 = fmaxf(0.0f, a0 * W[0] + a1 * W[3] + a2 * W[6] + b[0]);
  float h1 = fmaxf(0.0f, a0 * W[1] + a1 * W[4] + a2 * W[7] + b[1]);
  float h2 = fmaxf(0.0f, a0 * W[2] + a1 * W[5] + a2 * W[8] + b[2]);
  ((float4*)sNext)[i] = make_float4(h0 * n, h1 * n, h2 * n, 0.0f);
}

// Layer 5 (3->3) + layer-6 pre-transform: sB = (relu(...W5,b5) @ W6) * n
__global__ void k_aggL5(const int* __restrict__ row_ptr, const int* __restrict__ perm,
                        const float* __restrict__ sPrev, const float* __restrict__ norm,
                        const float* __restrict__ W5, const float* __restrict__ b5,
                        const float* __restrict__ W6, float* __restrict__ sB, int N) {
  int i = blockIdx.x * BT + threadIdx.x;
  if (i >= N) return;
  int beg = row_ptr[i], end = row_ptr[i + 1];
  float a0 = 0.0f, a1 = 0.0f, a2 = 0.0f;
  for (int e = beg; e < end; ++e) {
    float4 m = ((const float4*)sPrev)[perm[e]];
    a0 += m.x;
    a1 += m.y;
    a2 += m.z;
  }
  float n = norm[i];
  a0 *= n; a1 *= n; a2 *= n;
  float h0 = fmaxf(0.0f, a0 * W5[0] + a1 * W5[3] + a2 * W5[6] + b5[0]);
  float h1 = fmaxf(0.0f, a0 * W5[1] + a1 * W5[4] + a2 * W5[7] + b5[1]);
  float h2 = fmaxf(0.0f, a0 * W5[2] + a1 * W5[5] + a2 * W5[8] + b5[2]);
  sB[i] = (h0 * W6[0] + h1 * W6[1] + h2 * W6[2]) * n;
}

// Layer 6 (scalar): out = relu(sum(sB[perm]) * n + b6)
__global__ void k_aggL6(const int* __restrict__ row_ptr, const int* __restrict__ perm,
                        const float* __restrict__ sB, const float* __restrict__ norm,
                        const float* __restrict__ b6, float* __restrict__ out, int N) {
  int i = blockIdx.x * BT + threadIdx.x;
  if (i >= N) return;
  int beg = row_ptr[i], end = row_ptr[i + 1];
  float t = 0.0f;
  for (int e = beg; e < end; ++e) t += sB[perm[e]];
  out[i] = fmaxf(0.0f, t * norm[i] + b6[0]);
}

extern "C" void kernel_launch(void* const* d_in, const int* in_sizes, int n_in,
                              void* d_out, int out_size, void* d_ws, size_t ws_size,
                              hipStream_t stream) {
  const float* feat = (const float*)d_in[0];
  const float* norm = (const float*)d_in[1];
  const int* src = (const int*)d_in[2];
  const int* dst = (const int*)d_in[3];
  const float* W1 = (const float*)d_in[4];
  const float* b1 = (const float*)d_in[5];
  const float* W2 = (const float*)d_in[6];
  const float* b2 = (const float*)d_in[7];
  const float* W3 = (const float*)d_in[8];
  const float* b3 = (const float*)d_in[9];
  const float* W4 = (const float*)d_in[10];
  const float* b4 = (const float*)d_in[11];
  const float* W5 = (const float*)d_in[12];
  const float* b5 = (const float*)d_in[13];
  const float* W6 = (const float*)d_in[14];
  const float* b6 = (const float*)d_in[15];
  float* out = (float*)d_out;

  const int N = in_sizes[0];
  const int E = in_sizes[2];
  const int nbNode = (N + BT - 1) / BT;       // 3907
  const int nbEdge = ((E + 3) / 4 + BT - 1) / BT;

  // Workspace layout (ints/floats, N=1e6, E=16e6  =>  ~112 MB):
  // perm[E] | row_ptr[N+1] | cursor[N] | count[N] | partial[4096] | s0B[N] | sA[4N] | sA2[4N]
  int* perm = (int*)d_ws;
  int* row_ptr = perm + (size_t)E;
  int* cursor = row_ptr + (size_t)N + 1;
  int* count = cursor + (size_t)N;
  int* partial = count + (size_t)N;
  float* s0B = (float*)(partial + 4096);  // layer-1 input, reused as layer-5 output
  float* sA = s0B + (size_t)N;
  float* sA2 = sA + (size_t)4 * N;

  // --- Build CSR (counting sort by dst) ---
  k_zero<<<nbNode, BT, 0, stream>>>(count, N);
  k_init<<<nbNode, BT, 0, stream>>>(feat, norm, s0B, N);
  k_hist<<<nbEdge, BT, 0, stream>>>(dst, count, E);
  k_blockSum<<<nbNode, BT, 0, stream>>>(count, partial, N);
  k_scanPartials<<<1, BT, 0, stream>>>(partial, nbNode);
  k_scanFinal<<<nbNode, BT, 0, stream>>>(count, partial, row_ptr, cursor, N, E);
  k_scatter<<<nbEdge, BT, 0, stream>>>(src, dst, cursor, perm, E);

  // --- 6 fused layers (no atomics) ---
  k_aggL1<<<nbNode, BT, 0, stream>>>(row_ptr, perm, s0B, norm, W1, b1, sA, N);
  k_agg3<<<nbNode, BT, 0, stream>>>(row_ptr, perm, sA, norm, W2, b2, sA2, N);
  k_agg3<<<nbNode, BT, 0, stream>>>(row_ptr, perm, sA2, norm, W3, b3, sA, N);
  k_agg3<<<nbNode, BT, 0, stream>>>(row_ptr, perm, sA, norm, W4, b4, sA2, N);
  k_aggL5<<<nbNode, BT, 0, stream>>>(row_ptr, perm, sA2, norm, W5, b5, W6, s0B, N);
  k_aggL6<<<nbNode, BT, 0, stream>>>(row_ptr, perm, s0B, norm, b6, out, N);
}

// Round 3
// 1810.128 us; speedup vs baseline: 6.1306x; 2.0520x over previous
//
#include <hip/hip_runtime.h>

// ---------------------------------------------------------------------------
// GCN, 6 layers, N=1M nodes, E=16M edges.
// R3: coarse bucket partition (2048 buckets of 512 dst-nodes) instead of full
// CSR sort. Build uses LDS histograms + coalesced transposes + linear scan +
// LDS-cursor scatter (no global atomics anywhere). Each layer: one block per
// bucket, LDS float accumulators (ds_add_f32), coalesced packed-edge stream,
// fused norm/GEMV/ReLU epilogue. Packed edge = (src<<9)|(dst&511) in one u32.
// Layer 6 applies W6 before aggregation (right-mult commutes with A).
// ---------------------------------------------------------------------------

#define BT 256
#define NBLK 256          // partition blocks
#define BSHIFT 9          // 512 nodes per bucket
#define BSIZE 512
#define LMASK 511
#define NBKT 2048         // padded bucket count (>= ceil(1e6/512)=1954)

// s0 = feat * norm
__global__ void k_init(const float* __restrict__ feat, const float* __restrict__ norm,
                       float* __restrict__ s0, int N) {
  int i = blockIdx.x * BT + threadIdx.x;
  if (i < N) s0[i] = feat[i] * norm[i];
}

// P1: per-block LDS histogram of dst buckets -> histB[block][bucket] (coalesced)
__global__ void k_phist(const int* __restrict__ dst, int* __restrict__ histB,
                        int E, int chunk) {
  __shared__ int h[NBKT];
  for (int i = threadIdx.x; i < NBKT; i += BT) h[i] = 0;
  __syncthreads();
  int b = blockIdx.x;
  int beg = b * chunk, end = min(beg + chunk, E);
  for (int i = beg + threadIdx.x; i < end; i += BT)
    atomicAdd(&h[dst[i] >> BSHIFT], 1);
  __syncthreads();
  for (int k = threadIdx.x; k < NBKT; k += BT)
    histB[b * NBKT + k] = h[k];
}

// Tiled transpose: in[R][C] -> out[C][R].  R,C multiples of 64.  grid(C/64,R/64)
__global__ void k_transp(const int* __restrict__ in, int* __restrict__ out, int R, int C) {
  __shared__ int tile[64][65];
  int c0 = blockIdx.x * 64, r0 = blockIdx.y * 64;
  int tx = threadIdx.x & 63, ty = threadIdx.x >> 6;  // 64 x 4
  for (int j = 0; j < 16; ++j) {
    int r = ty + j * 4;
    tile[r][tx] = in[(r0 + r) * C + c0 + tx];
  }
  __syncthreads();
  for (int j = 0; j < 16; ++j) {
    int r = ty + j * 4;
    out[(c0 + r) * R + r0 + tx] = tile[tx][r];
  }
}

// scan A: per-block sums of data[M] -> partial[M/BT]
__global__ void k_blockSum(const int* __restrict__ data, int* __restrict__ partial, int M) {
  __shared__ int tmp[BT];
  int i = blockIdx.x * BT + threadIdx.x;
  tmp[threadIdx.x] = (i < M) ? data[i] : 0;
  __syncthreads();
  for (int off = BT / 2; off > 0; off >>= 1) {
    if (threadIdx.x < off) tmp[threadIdx.x] += tmp[threadIdx.x + off];
    __syncthreads();
  }
  if (threadIdx.x == 0) partial[blockIdx.x] = tmp[0];
}

// scan B: exclusive scan of partials in place (single block, loops)
__global__ void k_scanPartials(int* __restrict__ partial, int nb) {
  __shared__ int tmp[BT];
  __shared__ int carry;
  int t = threadIdx.x;
  if (t == 0) carry = 0;
  __syncthreads();
  for (int base = 0; base < nb; base += BT) {
    int i = base + t;
    int v = (i < nb) ? partial[i] : 0;
    tmp[t] = v;
    __syncthreads();
    for (int off = 1; off < BT; off <<= 1) {
      int x = 0;
      if (t >= off) x = tmp[t - off];
      __syncthreads();
      tmp[t] += x;
      __syncthreads();
    }
    if (i < nb) partial[i] = tmp[t] - v + carry;
    __syncthreads();
    if (t == BT - 1) carry += tmp[BT - 1];
    __syncthreads();
  }
}

// scan C: final exclusive scan in place
__global__ void k_scanFinal(int* __restrict__ data, const int* __restrict__ partial, int M) {
  __shared__ int tmp[BT];
  int t = threadIdx.x;
  int i = blockIdx.x * BT + t;
  int v = (i < M) ? data[i] : 0;
  tmp[t] = v;
  __syncthreads();
  for (int off = 1; off < BT; off <<= 1) {
    int x = 0;
    if (t >= off) x = tmp[t - off];
    __syncthreads();
    tmp[t] += x;
    __syncthreads();
  }
  if (i < M) data[i] = tmp[t] - v + partial[blockIdx.x];
}

// P2: scatter packed edges using per-block LDS cursors (no global atomics)
__global__ void k_pscatter(const int* __restrict__ src, const int* __restrict__ dst,
                           const int* __restrict__ scanT, unsigned int* __restrict__ packed,
                           int E, int chunk) {
  __shared__ int cur[NBKT];
  int b = blockIdx.x;
  for (int k = threadIdx.x; k < NBKT; k += BT) cur[k] = scanT[b * NBKT + k];
  __syncthreads();
  int beg = b * chunk, end = min(beg + chunk, E);
  for (int i = beg + threadIdx.x; i < end; i += BT) {
    int s = src[i], d = dst[i];
    int pos = atomicAdd(&cur[d >> BSHIFT], 1);
    packed[pos] = ((unsigned)s << BSHIFT) | (unsigned)(d & LMASK);
  }
}

// bucket boundaries for layer kernels: row b=0 of scanT = bucket starts.
// Layer 1 (1->3): scalar gather, scalar LDS agg, then W1 GEMV epilogue.
__global__ void k_layer1(const int* __restrict__ scanT, const unsigned int* __restrict__ packed,
                         const float* __restrict__ s0, const float* __restrict__ norm,
                         const float* __restrict__ W1, const float* __restrict__ b1,
                         float* __restrict__ sNext, int N) {
  __shared__ float a[BSIZE];
  int k = blockIdx.x;
  for (int i = threadIdx.x; i < BSIZE; i += BT) a[i] = 0.0f;
  int beg = scanT[k], end = scanT[k + 1];
  __syncthreads();
  for (int e = beg + threadIdx.x; e < end; e += BT) {
    unsigned p = packed[e];
    atomicAdd(&a[p & LMASK], s0[p >> BSHIFT]);
  }
  __syncthreads();
  int node0 = k << BSHIFT;
  for (int t = threadIdx.x; t < BSIZE; t += BT) {
    int node = node0 + t;
    if (node >= N) break;
    float n = norm[node];
    float pre = a[t] * n;
    float h0 = fmaxf(0.0f, pre * W1[0] + b1[0]);
    float h1 = fmaxf(0.0f, pre * W1[1] + b1[1]);
    float h2 = fmaxf(0.0f, pre * W1[2] + b1[2]);
    ((float4*)sNext)[node] = make_float4(h0 * n, h1 * n, h2 * n, 0.0f);
  }
}

// Layers 2-4 (3->3)
__global__ void k_layer3(const int* __restrict__ scanT, const unsigned int* __restrict__ packed,
                         const float* __restrict__ sPrev, const float* __restrict__ norm,
                         const float* __restrict__ W, const float* __restrict__ bias,
                         float* __restrict__ sNext, int N) {
  __shared__ float a0[BSIZE], a1[BSIZE], a2[BSIZE];
  int k = blockIdx.x;
  for (int i = threadIdx.x; i < BSIZE; i += BT) { a0[i] = 0.0f; a1[i] = 0.0f; a2[i] = 0.0f; }
  int beg = scanT[k], end = scanT[k + 1];
  __syncthreads();
  for (int e = beg + threadIdx.x; e < end; e += BT) {
    unsigned p = packed[e];
    int loc = p & LMASK;
    float4 m = ((const float4*)sPrev)[p >> BSHIFT];
    atomicAdd(&a0[loc], m.x);
    atomicAdd(&a1[loc], m.y);
    atomicAdd(&a2[loc], m.z);
  }
  __syncthreads();
  int node0 = k << BSHIFT;
  for (int t = threadIdx.x; t < BSIZE; t += BT) {
    int node = node0 + t;
    if (node >= N) break;
    float n = norm[node];
    float x0 = a0[t] * n, x1 = a1[t] * n, x2 = a2[t] * n;
    float h0 = fmaxf(0.0f, x0 * W[0] + x1 * W[3] + x2 * W[6] + bias[0]);
    float h1 = fmaxf(0.0f, x0 * W[1] + x1 * W[4] + x2 * W[7] + bias[1]);
    float h2 = fmaxf(0.0f, x0 * W[2] + x1 * W[5] + x2 * W[8] + bias[2]);
    ((float4*)sNext)[node] = make_float4(h0 * n, h1 * n, h2 * n, 0.0f);
  }
}

// Layer 5 (3->3) + layer-6 pre-transform: sB = (relu(agg*n @ W5 + b5) @ W6) * n
__global__ void k_layer5(const int* __restrict__ scanT, const unsigned int* __restrict__ packed,
                         const float* __restrict__ sPrev, const float* __restrict__ norm,
                         const float* __restrict__ W5, const float* __restrict__ b5,
                         const float* __restrict__ W6, float* __restrict__ sB, int N) {
  __shared__ float a0[BSIZE], a1[BSIZE], a2[BSIZE];
  int k = blockIdx.x;
  for (int i = threadIdx.x; i < BSIZE; i += BT) { a0[i] = 0.0f; a1[i] = 0.0f; a2[i] = 0.0f; }
  int beg = scanT[k], end = scanT[k + 1];
  __syncthreads();
  for (int e = beg + threadIdx.x; e < end; e += BT) {
    unsigned p = packed[e];
    int loc = p & LMASK;
    float4 m = ((const float4*)sPrev)[p >> BSHIFT];
    atomicAdd(&a0[loc], m.x);
    atomicAdd(&a1[loc], m.y);
    atomicAdd(&a2[loc], m.z);
  }
  __syncthreads();
  int node0 = k << BSHIFT;
  for (int t = threadIdx.x; t < BSIZE; t += BT) {
    int node = node0 + t;
    if (node >= N) break;
    float n = norm[node];
    float x0 = a0[t] * n, x1 = a1[t] * n, x2 = a2[t] * n;
    float h0 = fmaxf(0.0f, x0 * W5[0] + x1 * W5[3] + x2 * W5[6] + b5[0]);
    float h1 = fmaxf(0.0f, x0 * W5[1] + x1 * W5[4] + x2 * W5[7] + b5[1]);
    float h2 = fmaxf(0.0f, x0 * W5[2] + x1 * W5[5] + x2 * W5[8] + b5[2]);
    sB[node] = (h0 * W6[0] + h1 * W6[1] + h2 * W6[2]) * n;
  }
}

// Layer 6 (scalar): out = relu(agg * n + b6)
__global__ void k_layer6(const int* __restrict__ scanT, const unsigned int* __restrict__ packed,
                         const float* __restrict__ sB, const float* __restrict__ norm,
                         const float* __restrict__ b6, float* __restrict__ out, int N) {
  __shared__ float a[BSIZE];
  int k = blockIdx.x;
  for (int i = threadIdx.x; i < BSIZE; i += BT) a[i] = 0.0f;
  int beg = scanT[k], end = scanT[k + 1];
  __syncthreads();
  for (int e = beg + threadIdx.x; e < end; e += BT) {
    unsigned p = packed[e];
    atomicAdd(&a[p & LMASK], sB[p >> BSHIFT]);
  }
  __syncthreads();
  int node0 = k << BSHIFT;
  for (int t = threadIdx.x; t < BSIZE; t += BT) {
    int node = node0 + t;
    if (node >= N) break;
    out[node] = fmaxf(0.0f, a[t] * norm[node] + b6[0]);
  }
}

extern "C" void kernel_launch(void* const* d_in, const int* in_sizes, int n_in,
                              void* d_out, int out_size, void* d_ws, size_t ws_size,
                              hipStream_t stream) {
  const float* feat = (const float*)d_in[0];
  const float* norm = (const float*)d_in[1];
  const int* src = (const int*)d_in[2];
  const int* dst = (const int*)d_in[3];
  const float* W1 = (const float*)d_in[4];
  const float* b1 = (const float*)d_in[5];
  const float* W2 = (const float*)d_in[6];
  const float* b2 = (const float*)d_in[7];
  const float* W3 = (const float*)d_in[8];
  const float* b3 = (const float*)d_in[9];
  const float* W4 = (const float*)d_in[10];
  const float* b4 = (const float*)d_in[11];
  const float* W5 = (const float*)d_in[12];
  const float* b5 = (const float*)d_in[13];
  const float* W6 = (const float*)d_in[14];
  const float* b6 = (const float*)d_in[15];
  float* out = (float*)d_out;

  const int N = in_sizes[0];
  const int E = in_sizes[2];
  const int nbNode = (N + BT - 1) / BT;
  const int nBkt = (N + BSIZE - 1) >> BSHIFT;  // real buckets (<= NBKT)
  const int chunk = (E + NBLK - 1) / NBLK;
  const int M = NBKT * NBLK;                   // scan length = 524288

  // Workspace (ints unless noted):
  // packed[E] | histB[M] | histT[M] | scanT[M] | partial[M/BT] | s0B[N]f | sA[4N]f | sA2[4N]f
  unsigned int* packed = (unsigned int*)d_ws;
  int* histB = (int*)(packed + (size_t)E);
  int* histT = histB + (size_t)M;
  int* scanT = histT + (size_t)M;
  int* partial = scanT + (size_t)M;
  float* s0B = (float*)(partial + M / BT);
  float* sA = s0B + (size_t)N;
  float* sA2 = sA + (size_t)4 * N;

  // --- Build bucket partition ---
  k_init<<<nbNode, BT, 0, stream>>>(feat, norm, s0B, N);
  k_phist<<<NBLK, BT, 0, stream>>>(dst, histB, E, chunk);
  {
    dim3 g1(NBKT / 64, NBLK / 64);  // histB[NBLK][NBKT] -> histT[NBKT][NBLK]
    k_transp<<<g1, BT, 0, stream>>>(histB, histT, NBLK, NBKT);
  }
  k_blockSum<<<M / BT, BT, 0, stream>>>(histT, partial, M);
  k_scanPartials<<<1, BT, 0, stream>>>(partial, M / BT);
  k_scanFinal<<<M / BT, BT, 0, stream>>>(histT, partial, M);
  {
    dim3 g2(NBLK / 64, NBKT / 64);  // histT[NBKT][NBLK] (scanned) -> scanT[NBLK][NBKT]
    k_transp<<<g2, BT, 0, stream>>>(histT, scanT, NBKT, NBLK);
  }
  k_pscatter<<<NBLK, BT, 0, stream>>>(src, dst, scanT, packed, E, chunk);

  // --- 6 fused layers (row 0 of scanT = bucket starts) ---
  k_layer1<<<nBkt, BT, 0, stream>>>(scanT, packed, s0B, norm, W1, b1, sA, N);
  k_layer3<<<nBkt, BT, 0, stream>>>(scanT, packed, sA, norm, W2, b2, sA2, N);
  k_layer3<<<nBkt, BT, 0, stream>>>(scanT, packed, sA2, norm, W3, b3, sA, N);
  k_layer3<<<nBkt, BT, 0, stream>>>(scanT, packed, sA, norm, W4, b4, sA2, N);
  k_layer5<<<nBkt, BT, 0, stream>>>(scanT, packed, sA2, norm, W5, b5, W6, s0B, N);
  k_layer6<<<nBkt, BT, 0, stream>>>(scanT, packed, s0B, norm, b6, out, N);
}

// Round 4
// 1555.990 us; speedup vs baseline: 7.1319x; 1.1633x over previous
//
#include <hip/hip_runtime.h>

// ---------------------------------------------------------------------------
// GCN, 6 layers, N=1M nodes, E=16M edges.
// R4: 256 coarse buckets of 4096 dst-nodes (was 2048x512). Packed edge =
// (src<<12)|(dst&4095) fits u32 exactly (src<2^20). Build: LDS hist (256 bins)
// -> transpose -> scan -> transpose -> LDS-cursor scatter. With 256 cursors
// per block, (block,bucket) write runs ~244 edges => full-line writes, no
// write amplification. Layers: one 1024-thread block per bucket, 48KB LDS
// accumulator (3x4096 f32), uint4 edge loads, fused norm/GEMV/ReLU epilogue.
// Layer 6 applies W6 before aggregation (right-mult commutes with A).
// ---------------------------------------------------------------------------

#define BT 256            // build-kernel block size
#define NBLK 256          // partition blocks
#define BSHIFT 12         // 4096 nodes per bucket
#define BSIZE 4096
#define LMASK 4095
#define NBKT 256          // padded bucket count (>= ceil(1e6/4096)=245)
#define M (NBLK * NBKT)   // 65536
#define BTL 1024          // layer-kernel block size

// s0 = feat * norm
__global__ void k_init(const float* __restrict__ feat, const float* __restrict__ norm,
                       float* __restrict__ s0, int N) {
  int i = blockIdx.x * BT + threadIdx.x;
  if (i < N) s0[i] = feat[i] * norm[i];
}

// P1: per-block LDS histogram of dst buckets (256 bins)
__global__ void k_phist(const int* __restrict__ dst, int* __restrict__ histB,
                        int E, int chunk) {
  __shared__ int h[NBKT];
  if (threadIdx.x < NBKT) h[threadIdx.x] = 0;
  __syncthreads();
  int b = blockIdx.x;
  int beg = b * chunk, end = min(beg + chunk, E);
  int i = beg + (int)threadIdx.x * 4;  // beg is 16B-aligned (chunk % 4 == 0)
  for (; i + 3 < end; i += BT * 4) {
    int4 v = *(const int4*)(dst + i);
    atomicAdd(&h[v.x >> BSHIFT], 1);
    atomicAdd(&h[v.y >> BSHIFT], 1);
    atomicAdd(&h[v.z >> BSHIFT], 1);
    atomicAdd(&h[v.w >> BSHIFT], 1);
  }
  for (; i < end; ++i) atomicAdd(&h[dst[i] >> BSHIFT], 1);
  __syncthreads();
  if (threadIdx.x < NBKT) histB[b * NBKT + threadIdx.x] = h[threadIdx.x];
}

// Tiled transpose: in[R][C] -> out[C][R]. R,C multiples of 64. grid(C/64,R/64)
__global__ void k_transp(const int* __restrict__ in, int* __restrict__ out, int R, int C) {
  __shared__ int tile[64][65];
  int c0 = blockIdx.x * 64, r0 = blockIdx.y * 64;
  int tx = threadIdx.x & 63, ty = threadIdx.x >> 6;  // 64 x 4
  for (int j = 0; j < 16; ++j) {
    int r = ty + j * 4;
    tile[r][tx] = in[(r0 + r) * C + c0 + tx];
  }
  __syncthreads();
  for (int j = 0; j < 16; ++j) {
    int r = ty + j * 4;
    out[(c0 + r) * R + r0 + tx] = tile[tx][r];
  }
}

// scan A: per-block sums
__global__ void k_blockSum(const int* __restrict__ data, int* __restrict__ partial, int Mlen) {
  __shared__ int tmp[BT];
  int i = blockIdx.x * BT + threadIdx.x;
  tmp[threadIdx.x] = (i < Mlen) ? data[i] : 0;
  __syncthreads();
  for (int off = BT / 2; off > 0; off >>= 1) {
    if (threadIdx.x < off) tmp[threadIdx.x] += tmp[threadIdx.x + off];
    __syncthreads();
  }
  if (threadIdx.x == 0) partial[blockIdx.x] = tmp[0];
}

// scan B: exclusive scan of partials in place (single block)
__global__ void k_scanPartials(int* __restrict__ partial, int nb) {
  __shared__ int tmp[BT];
  __shared__ int carry;
  int t = threadIdx.x;
  if (t == 0) carry = 0;
  __syncthreads();
  for (int base = 0; base < nb; base += BT) {
    int i = base + t;
    int v = (i < nb) ? partial[i] : 0;
    tmp[t] = v;
    __syncthreads();
    for (int off = 1; off < BT; off <<= 1) {
      int x = 0;
      if (t >= off) x = tmp[t - off];
      __syncthreads();
      tmp[t] += x;
      __syncthreads();
    }
    if (i < nb) partial[i] = tmp[t] - v + carry;
    __syncthreads();
    if (t == BT - 1) carry += tmp[BT - 1];
    __syncthreads();
  }
}

// scan C: final exclusive scan in place
__global__ void k_scanFinal(int* __restrict__ data, const int* __restrict__ partial, int Mlen) {
  __shared__ int tmp[BT];
  int t = threadIdx.x;
  int i = blockIdx.x * BT + t;
  int v = (i < Mlen) ? data[i] : 0;
  tmp[t] = v;
  __syncthreads();
  for (int off = 1; off < BT; off <<= 1) {
    int x = 0;
    if (t >= off) x = tmp[t - off];
    __syncthreads();
    tmp[t] += x;
    __syncthreads();
  }
  if (i < Mlen) data[i] = tmp[t] - v + partial[blockIdx.x];
}

// P2: scatter packed edges with per-block LDS cursors (256 bins)
__global__ void k_pscatter(const int* __restrict__ src, const int* __restrict__ dst,
                           const int* __restrict__ scanT, unsigned int* __restrict__ packed,
                           int E, int chunk) {
  __shared__ int cur[NBKT];
  int b = blockIdx.x;
  if (threadIdx.x < NBKT) cur[threadIdx.x] = scanT[b * NBKT + threadIdx.x];
  __syncthreads();
  int beg = b * chunk, end = min(beg + chunk, E);
  int i = beg + (int)threadIdx.x * 4;
  for (; i + 3 < end; i += BT * 4) {
    int4 u = *(const int4*)(src + i);
    int4 v = *(const int4*)(dst + i);
    int p;
    p = atomicAdd(&cur[v.x >> BSHIFT], 1);
    packed[p] = ((unsigned)u.x << BSHIFT) | (unsigned)(v.x & LMASK);
    p = atomicAdd(&cur[v.y >> BSHIFT], 1);
    packed[p] = ((unsigned)u.y << BSHIFT) | (unsigned)(v.y & LMASK);
    p = atomicAdd(&cur[v.z >> BSHIFT], 1);
    packed[p] = ((unsigned)u.z << BSHIFT) | (unsigned)(v.z & LMASK);
    p = atomicAdd(&cur[v.w >> BSHIFT], 1);
    packed[p] = ((unsigned)u.w << BSHIFT) | (unsigned)(v.w & LMASK);
  }
  for (; i < end; ++i) {
    int p = atomicAdd(&cur[dst[i] >> BSHIFT], 1);
    packed[p] = ((unsigned)src[i] << BSHIFT) | (unsigned)(dst[i] & LMASK);
  }
}

// --- layer kernels: one block per bucket, bucket start = scanT[k] (row 0) ---

#define ACC3(p)                                             \
  {                                                         \
    unsigned pp = (p);                                      \
    float4 m = ((const float4*)sPrev)[pp >> BSHIFT];        \
    int loc = pp & LMASK;                                   \
    atomicAdd(&a0[loc], m.x);                               \
    atomicAdd(&a1[loc], m.y);                               \
    atomicAdd(&a2[loc], m.z);                               \
  }

#define ACC1(p)                                             \
  {                                                         \
    unsigned pp = (p);                                      \
    atomicAdd(&a[pp & LMASK], sIn[pp >> BSHIFT]);           \
  }

// Layer 1 (1->3): scalar gather + scalar LDS agg + W1 GEMV epilogue
__global__ __launch_bounds__(BTL) void k_layer1(
    const int* __restrict__ scanT, const unsigned int* __restrict__ packed,
    const float* __restrict__ sIn, const float* __restrict__ norm,
    const float* __restrict__ W1, const float* __restrict__ b1,
    float* __restrict__ sNext, int N) {
  __shared__ float a[BSIZE];
  int k = blockIdx.x;
  for (int i = threadIdx.x; i < BSIZE; i += BTL) a[i] = 0.0f;
  int beg = scanT[k], end = scanT[k + 1];
  __syncthreads();
  int abeg = min(end, (beg + 3) & ~3);
  int t = beg + (int)threadIdx.x;
  if (t < abeg) ACC1(packed[t]);
  int i = abeg + (int)threadIdx.x * 4;
  for (; i + 3 < end; i += BTL * 4) {
    uint4 p4 = *(const uint4*)(packed + i);
    ACC1(p4.x) ACC1(p4.y) ACC1(p4.z) ACC1(p4.w)
  }
  for (; i < end; ++i) ACC1(packed[i]);
  __syncthreads();
  int node0 = k << BSHIFT;
  for (int tt = threadIdx.x; tt < BSIZE; tt += BTL) {
    int node = node0 + tt;
    if (node >= N) break;
    float n = norm[node];
    float pre = a[tt] * n;
    float h0 = fmaxf(0.0f, pre * W1[0] + b1[0]);
    float h1 = fmaxf(0.0f, pre * W1[1] + b1[1]);
    float h2 = fmaxf(0.0f, pre * W1[2] + b1[2]);
    ((float4*)sNext)[node] = make_float4(h0 * n, h1 * n, h2 * n, 0.0f);
  }
}

// Layers 2-4 (3->3)
__global__ __launch_bounds__(BTL) void k_layer3(
    const int* __restrict__ scanT, const unsigned int* __restrict__ packed,
    const float* __restrict__ sPrev, const float* __restrict__ norm,
    const float* __restrict__ W, const float* __restrict__ bias,
    float* __restrict__ sNext, int N) {
  __shared__ float a0[BSIZE], a1[BSIZE], a2[BSIZE];
  int k = blockIdx.x;
  for (int i = threadIdx.x; i < BSIZE; i += BTL) { a0[i] = 0.0f; a1[i] = 0.0f; a2[i] = 0.0f; }
  int beg = scanT[k], end = scanT[k + 1];
  __syncthreads();
  int abeg = min(end, (beg + 3) & ~3);
  int t = beg + (int)threadIdx.x;
  if (t < abeg) ACC3(packed[t]);
  int i = abeg + (int)threadIdx.x * 4;
  for (; i + 3 < end; i += BTL * 4) {
    uint4 p4 = *(const uint4*)(packed + i);
    ACC3(p4.x) ACC3(p4.y) ACC3(p4.z) ACC3(p4.w)
  }
  for (; i < end; ++i) ACC3(packed[i]);
  __syncthreads();
  int node0 = k << BSHIFT;
  for (int tt = threadIdx.x; tt < BSIZE; tt += BTL) {
    int node = node0 + tt;
    if (node >= N) break;
    float n = norm[node];
    float x0 = a0[tt] * n, x1 = a1[tt] * n, x2 = a2[tt] * n;
    float h0 = fmaxf(0.0f, x0 * W[0] + x1 * W[3] + x2 * W[6] + bias[0]);
    float h1 = fmaxf(0.0f, x0 * W[1] + x1 * W[4] + x2 * W[7] + bias[1]);
    float h2 = fmaxf(0.0f, x0 * W[2] + x1 * W[5] + x2 * W[8] + bias[2]);
    ((float4*)sNext)[node] = make_float4(h0 * n, h1 * n, h2 * n, 0.0f);
  }
}

// Layer 5 (3->3) + layer-6 pre-transform: sB = (relu(agg*n @ W5 + b5) @ W6) * n
__global__ __launch_bounds__(BTL) void k_layer5(
    const int* __restrict__ scanT, const unsigned int* __restrict__ packed,
    const float* __restrict__ sPrev, const float* __restrict__ norm,
    const float* __restrict__ W5, const float* __restrict__ b5,
    const float* __restrict__ W6, float* __restrict__ sB, int N) {
  __shared__ float a0[BSIZE], a1[BSIZE], a2[BSIZE];
  int k = blockIdx.x;
  for (int i = threadIdx.x; i < BSIZE; i += BTL) { a0[i] = 0.0f; a1[i] = 0.0f; a2[i] = 0.0f; }
  int beg = scanT[k], end = scanT[k + 1];
  __syncthreads();
  int abeg = min(end, (beg + 3) & ~3);
  int t = beg + (int)threadIdx.x;
  if (t < abeg) ACC3(packed[t]);
  int i = abeg + (int)threadIdx.x * 4;
  for (; i + 3 < end; i += BTL * 4) {
    uint4 p4 = *(const uint4*)(packed + i);
    ACC3(p4.x) ACC3(p4.y) ACC3(p4.z) ACC3(p4.w)
  }
  for (; i < end; ++i) ACC3(packed[i]);
  __syncthreads();
  int node0 = k << BSHIFT;
  for (int tt = threadIdx.x; tt < BSIZE; tt += BTL) {
    int node = node0 + tt;
    if (node >= N) break;
    float n = norm[node];
    float x0 = a0[tt] * n, x1 = a1[tt] * n, x2 = a2[tt] * n;
    float h0 = fmaxf(0.0f, x0 * W5[0] + x1 * W5[3] + x2 * W5[6] + b5[0]);
    float h1 = fmaxf(0.0f, x0 * W5[1] + x1 * W5[4] + x2 * W5[7] + b5[1]);
    float h2 = fmaxf(0.0f, x0 * W5[2] + x1 * W5[5] + x2 * W5[8] + b5[2]);
    sB[node] = (h0 * W6[0] + h1 * W6[1] + h2 * W6[2]) * n;
  }
}

// Layer 6 (scalar): out = relu(agg * n + b6)
__global__ __launch_bounds__(BTL) void k_layer6(
    const int* __restrict__ scanT, const unsigned int* __restrict__ packed,
    const float* __restrict__ sIn, const float* __restrict__ norm,
    const float* __restrict__ b6, float* __restrict__ out, int N) {
  __shared__ float a[BSIZE];
  int k = blockIdx.x;
  for (int i = threadIdx.x; i < BSIZE; i += BTL) a[i] = 0.0f;
  int beg = scanT[k], end = scanT[k + 1];
  __syncthreads();
  int abeg = min(end, (beg + 3) & ~3);
  int t = beg + (int)threadIdx.x;
  if (t < abeg) ACC1(packed[t]);
  int i = abeg + (int)threadIdx.x * 4;
  for (; i + 3 < end; i += BTL * 4) {
    uint4 p4 = *(const uint4*)(packed + i);
    ACC1(p4.x) ACC1(p4.y) ACC1(p4.z) ACC1(p4.w)
  }
  for (; i < end; ++i) ACC1(packed[i]);
  __syncthreads();
  int node0 = k << BSHIFT;
  for (int tt = threadIdx.x; tt < BSIZE; tt += BTL) {
    int node = node0 + tt;
    if (node >= N) break;
    out[node] = fmaxf(0.0f, a[tt] * norm[node] + b6[0]);
  }
}

extern "C" void kernel_launch(void* const* d_in, const int* in_sizes, int n_in,
                              void* d_out, int out_size, void* d_ws, size_t ws_size,
                              hipStream_t stream) {
  const float* feat = (const float*)d_in[0];
  const float* norm = (const float*)d_in[1];
  const int* src = (const int*)d_in[2];
  const int* dst = (const int*)d_in[3];
  const float* W1 = (const float*)d_in[4];
  const float* b1 = (const float*)d_in[5];
  const float* W2 = (const float*)d_in[6];
  const float* b2 = (const float*)d_in[7];
  const float* W3 = (const float*)d_in[8];
  const float* b3 = (const float*)d_in[9];
  const float* W4 = (const float*)d_in[10];
  const float* b4 = (const float*)d_in[11];
  const float* W5 = (const float*)d_in[12];
  const float* b5 = (const float*)d_in[13];
  const float* W6 = (const float*)d_in[14];
  const float* b6 = (const float*)d_in[15];
  float* out = (float*)d_out;

  const int N = in_sizes[0];
  const int E = in_sizes[2];
  const int nbNode = (N + BT - 1) / BT;
  const int nBkt = (N + BSIZE - 1) >> BSHIFT;                 // 245
  const int chunk = (((E + NBLK - 1) / NBLK) + 3) & ~3;       // 16B-aligned chunks

  // Workspace: packed[E] | histB[M] | histT[M] | scanT[M] | partial[M/BT] |
  //            s0B[N]f | sA[4N]f | sA2[4N]f    (~101 MB)
  unsigned int* packed = (unsigned int*)d_ws;
  int* histB = (int*)(packed + (size_t)E);
  int* histT = histB + (size_t)M;
  int* scanT = histT + (size_t)M;
  int* partial = scanT + (size_t)M;
  float* s0B = (float*)(partial + M / BT);
  float* sA = s0B + (size_t)N;
  float* sA2 = sA + (size_t)4 * N;

  // --- Build bucket partition ---
  k_init<<<nbNode, BT, 0, stream>>>(feat, norm, s0B, N);
  k_phist<<<NBLK, BT, 0, stream>>>(dst, histB, E, chunk);
  {
    dim3 g1(NBKT / 64, NBLK / 64);  // histB[NBLK][NBKT] -> histT[NBKT][NBLK]
    k_transp<<<g1, BT, 0, stream>>>(histB, histT, NBLK, NBKT);
  }
  k_blockSum<<<M / BT, BT, 0, stream>>>(histT, partial, M);
  k_scanPartials<<<1, BT, 0, stream>>>(partial, M / BT);
  k_scanFinal<<<M / BT, BT, 0, stream>>>(histT, partial, M);
  {
    dim3 g2(NBLK / 64, NBKT / 64);  // histT[NBKT][NBLK] (scanned) -> scanT[NBLK][NBKT]
    k_transp<<<g2, BT, 0, stream>>>(histT, scanT, NBKT, NBLK);
  }
  k_pscatter<<<NBLK, BT, 0, stream>>>(src, dst, scanT, packed, E, chunk);

  // --- 6 fused layers (row 0 of scanT = bucket starts) ---
  k_layer1<<<nBkt, BTL, 0, stream>>>(scanT, packed, s0B, norm, W1, b1, sA, N);
  k_layer3<<<nBkt, BTL, 0, stream>>>(scanT, packed, sA, norm, W2, b2, sA2, N);
  k_layer3<<<nBkt, BTL, 0, stream>>>(scanT, packed, sA2, norm, W3, b3, sA, N);
  k_layer3<<<nBkt, BTL, 0, stream>>>(scanT, packed, sA, norm, W4, b4, sA2, N);
  k_layer5<<<nBkt, BTL, 0, stream>>>(scanT, packed, sA2, norm, W5, b5, W6, s0B, N);
  k_layer6<<<nBkt, BTL, 0, stream>>>(scanT, packed, s0B, norm, b6, out, N);
}

// Round 5
// 1546.984 us; speedup vs baseline: 7.1734x; 1.0058x over previous
//
#include <hip/hip_runtime.h>

// ---------------------------------------------------------------------------
// GCN, 6 layers, N=1M nodes, E=16M edges.
// R5: edges ordered by (dst_bucket[245 of 4096 nodes], src_superblock[4 of
// 256K nodes]). Packed edge = (src<<12)|(dst&4095). The src-superblock
// ordering gives gather temporal locality: the active src window is 4 MB
// (= one XCD's L2), and ~31 co-resident blocks per XCD sweep windows in
// lockstep, so each line gets ~8 uses while resident (was 1 use -> 784 MB
// L2-miss fills per layer). Layer kernels: one 1024-thread block per dst
// bucket, 48KB LDS accumulator, uint4 edge loads, fused norm/GEMV/ReLU.
// Layer 6 applies W6 before aggregation (right-mult commutes with A).
// ---------------------------------------------------------------------------

#define BT 256            // build-kernel block size
#define NBLK 256          // partition blocks
#define BSHIFT 12         // 4096 nodes per dst bucket
#define BSIZE 4096
#define LMASK 4095
#define SSH 18            // src super-block shift (256K nodes = 4MB float4 window)
#define NBINS 1024        // (dst_bucket<<2)|src_sb, padded (real: 245*4=980)
#define M (NBLK * NBINS)  // 262144
#define BTL 1024          // layer-kernel block size

__device__ __forceinline__ int edge_key(int s, int d) {
  return ((d >> BSHIFT) << 2) | (s >> SSH);
}

// s0 = feat * norm
__global__ void k_init(const float* __restrict__ feat, const float* __restrict__ norm,
                       float* __restrict__ s0, int N) {
  int i = blockIdx.x * BT + threadIdx.x;
  if (i < N) s0[i] = feat[i] * norm[i];
}

// P1: per-block LDS histogram of (dst_bucket, src_sb) bins
__global__ void k_phist(const int* __restrict__ src, const int* __restrict__ dst,
                        int* __restrict__ histB, int E, int chunk) {
  __shared__ int h[NBINS];
  for (int i = threadIdx.x; i < NBINS; i += BT) h[i] = 0;
  __syncthreads();
  int b = blockIdx.x;
  int beg = b * chunk, end = min(beg + chunk, E);
  int i = beg + (int)threadIdx.x * 4;  // beg is 16B-aligned (chunk % 4 == 0)
  for (; i + 3 < end; i += BT * 4) {
    int4 u = *(const int4*)(src + i);
    int4 v = *(const int4*)(dst + i);
    atomicAdd(&h[edge_key(u.x, v.x)], 1);
    atomicAdd(&h[edge_key(u.y, v.y)], 1);
    atomicAdd(&h[edge_key(u.z, v.z)], 1);
    atomicAdd(&h[edge_key(u.w, v.w)], 1);
  }
  for (; i < end; ++i) atomicAdd(&h[edge_key(src[i], dst[i])], 1);
  __syncthreads();
  for (int k = threadIdx.x; k < NBINS; k += BT) histB[b * NBINS + k] = h[k];
}

// Tiled transpose: in[R][C] -> out[C][R]. R,C multiples of 64. grid(C/64,R/64)
__global__ void k_transp(const int* __restrict__ in, int* __restrict__ out, int R, int C) {
  __shared__ int tile[64][65];
  int c0 = blockIdx.x * 64, r0 = blockIdx.y * 64;
  int tx = threadIdx.x & 63, ty = threadIdx.x >> 6;  // 64 x 4
  for (int j = 0; j < 16; ++j) {
    int r = ty + j * 4;
    tile[r][tx] = in[(r0 + r) * C + c0 + tx];
  }
  __syncthreads();
  for (int j = 0; j < 16; ++j) {
    int r = ty + j * 4;
    out[(c0 + r) * R + r0 + tx] = tile[tx][r];
  }
}

// scan A: per-block sums
__global__ void k_blockSum(const int* __restrict__ data, int* __restrict__ partial, int Mlen) {
  __shared__ int tmp[BT];
  int i = blockIdx.x * BT + threadIdx.x;
  tmp[threadIdx.x] = (i < Mlen) ? data[i] : 0;
  __syncthreads();
  for (int off = BT / 2; off > 0; off >>= 1) {
    if (threadIdx.x < off) tmp[threadIdx.x] += tmp[threadIdx.x + off];
    __syncthreads();
  }
  if (threadIdx.x == 0) partial[blockIdx.x] = tmp[0];
}

// scan B: exclusive scan of partials in place (single block)
__global__ void k_scanPartials(int* __restrict__ partial, int nb) {
  __shared__ int tmp[BT];
  __shared__ int carry;
  int t = threadIdx.x;
  if (t == 0) carry = 0;
  __syncthreads();
  for (int base = 0; base < nb; base += BT) {
    int i = base + t;
    int v = (i < nb) ? partial[i] : 0;
    tmp[t] = v;
    __syncthreads();
    for (int off = 1; off < BT; off <<= 1) {
      int x = 0;
      if (t >= off) x = tmp[t - off];
      __syncthreads();
      tmp[t] += x;
      __syncthreads();
    }
    if (i < nb) partial[i] = tmp[t] - v + carry;
    __syncthreads();
    if (t == BT - 1) carry += tmp[BT - 1];
    __syncthreads();
  }
}

// scan C: final exclusive scan in place
__global__ void k_scanFinal(int* __restrict__ data, const int* __restrict__ partial, int Mlen) {
  __shared__ int tmp[BT];
  int t = threadIdx.x;
  int i = blockIdx.x * BT + t;
  int v = (i < Mlen) ? data[i] : 0;
  tmp[t] = v;
  __syncthreads();
  for (int off = 1; off < BT; off <<= 1) {
    int x = 0;
    if (t >= off) x = tmp[t - off];
    __syncthreads();
    tmp[t] += x;
    __syncthreads();
  }
  if (i < Mlen) data[i] = tmp[t] - v + partial[blockIdx.x];
}

// P2: scatter packed edges with per-block LDS cursors (1024 bins)
__global__ void k_pscatter(const int* __restrict__ src, const int* __restrict__ dst,
                           const int* __restrict__ scanT, unsigned int* __restrict__ packed,
                           int E, int chunk) {
  __shared__ int cur[NBINS];
  int b = blockIdx.x;
  for (int k = threadIdx.x; k < NBINS; k += BT) cur[k] = scanT[b * NBINS + k];
  __syncthreads();
  int beg = b * chunk, end = min(beg + chunk, E);
  int i = beg + (int)threadIdx.x * 4;
  for (; i + 3 < end; i += BT * 4) {
    int4 u = *(const int4*)(src + i);
    int4 v = *(const int4*)(dst + i);
    int p;
    p = atomicAdd(&cur[edge_key(u.x, v.x)], 1);
    packed[p] = ((unsigned)u.x << BSHIFT) | (unsigned)(v.x & LMASK);
    p = atomicAdd(&cur[edge_key(u.y, v.y)], 1);
    packed[p] = ((unsigned)u.y << BSHIFT) | (unsigned)(v.y & LMASK);
    p = atomicAdd(&cur[edge_key(u.z, v.z)], 1);
    packed[p] = ((unsigned)u.z << BSHIFT) | (unsigned)(v.z & LMASK);
    p = atomicAdd(&cur[edge_key(u.w, v.w)], 1);
    packed[p] = ((unsigned)u.w << BSHIFT) | (unsigned)(v.w & LMASK);
  }
  for (; i < end; ++i) {
    int p = atomicAdd(&cur[edge_key(src[i], dst[i])], 1);
    packed[p] = ((unsigned)src[i] << BSHIFT) | (unsigned)(dst[i] & LMASK);
  }
}

// --- layer kernels: one block per dst bucket ---
// bucket k edge range = [scanT[4k], scanT[4k+4])  (row 0 of scanT = bin starts)

#define ACC3(p)                                             \
  {                                                         \
    unsigned pp = (p);                                      \
    float4 m = ((const float4*)sPrev)[pp >> BSHIFT];        \
    int loc = pp & LMASK;                                   \
    atomicAdd(&a0[loc], m.x);                               \
    atomicAdd(&a1[loc], m.y);                               \
    atomicAdd(&a2[loc], m.z);                               \
  }

#define ACC1(p)                                             \
  {                                                         \
    unsigned pp = (p);                                      \
    atomicAdd(&a[pp & LMASK], sIn[pp >> BSHIFT]);           \
  }

// Layer 1 (1->3)
__global__ __launch_bounds__(BTL) void k_layer1(
    const int* __restrict__ scanT, const unsigned int* __restrict__ packed,
    const float* __restrict__ sIn, const float* __restrict__ norm,
    const float* __restrict__ W1, const float* __restrict__ b1,
    float* __restrict__ sNext, int N) {
  __shared__ float a[BSIZE];
  int k = blockIdx.x;
  for (int i = threadIdx.x; i < BSIZE; i += BTL) a[i] = 0.0f;
  int beg = scanT[k << 2], end = scanT[(k << 2) + 4];
  __syncthreads();
  int abeg = min(end, (beg + 3) & ~3);
  int t = beg + (int)threadIdx.x;
  if (t < abeg) ACC1(packed[t]);
  int i = abeg + (int)threadIdx.x * 4;
  for (; i + 3 < end; i += BTL * 4) {
    uint4 p4 = *(const uint4*)(packed + i);
    ACC1(p4.x) ACC1(p4.y) ACC1(p4.z) ACC1(p4.w)
  }
  for (; i < end; ++i) ACC1(packed[i]);
  __syncthreads();
  int node0 = k << BSHIFT;
  for (int tt = threadIdx.x; tt < BSIZE; tt += BTL) {
    int node = node0 + tt;
    if (node >= N) break;
    float n = norm[node];
    float pre = a[tt] * n;
    float h0 = fmaxf(0.0f, pre * W1[0] + b1[0]);
    float h1 = fmaxf(0.0f, pre * W1[1] + b1[1]);
    float h2 = fmaxf(0.0f, pre * W1[2] + b1[2]);
    ((float4*)sNext)[node] = make_float4(h0 * n, h1 * n, h2 * n, 0.0f);
  }
}

// Layers 2-4 (3->3)
__global__ __launch_bounds__(BTL) void k_layer3(
    const int* __restrict__ scanT, const unsigned int* __restrict__ packed,
    const float* __restrict__ sPrev, const float* __restrict__ norm,
    const float* __restrict__ W, const float* __restrict__ bias,
    float* __restrict__ sNext, int N) {
  __shared__ float a0[BSIZE], a1[BSIZE], a2[BSIZE];
  int k = blockIdx.x;
  for (int i = threadIdx.x; i < BSIZE; i += BTL) { a0[i] = 0.0f; a1[i] = 0.0f; a2[i] = 0.0f; }
  int beg = scanT[k << 2], end = scanT[(k << 2) + 4];
  __syncthreads();
  int abeg = min(end, (beg + 3) & ~3);
  int t = beg + (int)threadIdx.x;
  if (t < abeg) ACC3(packed[t]);
  int i = abeg + (int)threadIdx.x * 4;
  for (; i + 3 < end; i += BTL * 4) {
    uint4 p4 = *(const uint4*)(packed + i);
    ACC3(p4.x) ACC3(p4.y) ACC3(p4.z) ACC3(p4.w)
  }
  for (; i < end; ++i) ACC3(packed[i]);
  __syncthreads();
  int node0 = k << BSHIFT;
  for (int tt = threadIdx.x; tt < BSIZE; tt += BTL) {
    int node = node0 + tt;
    if (node >= N) break;
    float n = norm[node];
    float x0 = a0[tt] * n, x1 = a1[tt] * n, x2 = a2[tt] * n;
    float h0 = fmaxf(0.0f, x0 * W[0] + x1 * W[3] + x2 * W[6] + bias[0]);
    float h1 = fmaxf(0.0f, x0 * W[1] + x1 * W[4] + x2 * W[7] + bias[1]);
    float h2 = fmaxf(0.0f, x0 * W[2] + x1 * W[5] + x2 * W[8] + bias[2]);
    ((float4*)sNext)[node] = make_float4(h0 * n, h1 * n, h2 * n, 0.0f);
  }
}

// Layer 5 (3->3) + layer-6 pre-transform: sB = (relu(agg*n @ W5 + b5) @ W6) * n
__global__ __launch_bounds__(BTL) void k_layer5(
    const int* __restrict__ scanT, const unsigned int* __restrict__ packed,
    const float* __restrict__ sPrev, const float* __restrict__ norm,
    const float* __restrict__ W5, const float* __restrict__ b5,
    const float* __restrict__ W6, float* __restrict__ sB, int N) {
  __shared__ float a0[BSIZE], a1[BSIZE], a2[BSIZE];
  int k = blockIdx.x;
  for (int i = threadIdx.x; i < BSIZE; i += BTL) { a0[i] = 0.0f; a1[i] = 0.0f; a2[i] = 0.0f; }
  int beg = scanT[k << 2], end = scanT[(k << 2) + 4];
  __syncthreads();
  int abeg = min(end, (beg + 3) & ~3);
  int t = beg + (int)threadIdx.x;
  if (t < abeg) ACC3(packed[t]);
  int i = abeg + (int)threadIdx.x * 4;
  for (; i + 3 < end; i += BTL * 4) {
    uint4 p4 = *(const uint4*)(packed + i);
    ACC3(p4.x) ACC3(p4.y) ACC3(p4.z) ACC3(p4.w)
  }
  for (; i < end; ++i) ACC3(packed[i]);
  __syncthreads();
  int node0 = k << BSHIFT;
  for (int tt = threadIdx.x; tt < BSIZE; tt += BTL) {
    int node = node0 + tt;
    if (node >= N) break;
    float n = norm[node];
    float x0 = a0[tt] * n, x1 = a1[tt] * n, x2 = a2[tt] * n;
    float h0 = fmaxf(0.0f, x0 * W5[0] + x1 * W5[3] + x2 * W5[6] + b5[0]);
    float h1 = fmaxf(0.0f, x0 * W5[1] + x1 * W5[4] + x2 * W5[7] + b5[1]);
    float h2 = fmaxf(0.0f, x0 * W5[2] + x1 * W5[5] + x2 * W5[8] + b5[2]);
    sB[node] = (h0 * W6[0] + h1 * W6[1] + h2 * W6[2]) * n;
  }
}

// Layer 6 (scalar): out = relu(agg * n + b6)
__global__ __launch_bounds__(BTL) void k_layer6(
    const int* __restrict__ scanT, const unsigned int* __restrict__ packed,
    const float* __restrict__ sIn, const float* __restrict__ norm,
    const float* __restrict__ b6, float* __restrict__ out, int N) {
  __shared__ float a[BSIZE];
  int k = blockIdx.x;
  for (int i = threadIdx.x; i < BSIZE; i += BTL) a[i] = 0.0f;
  int beg = scanT[k << 2], end = scanT[(k << 2) + 4];
  __syncthreads();
  int abeg = min(end, (beg + 3) & ~3);
  int t = beg + (int)threadIdx.x;
  if (t < abeg) ACC1(packed[t]);
  int i = abeg + (int)threadIdx.x * 4;
  for (; i + 3 < end; i += BTL * 4) {
    uint4 p4 = *(const uint4*)(packed + i);
    ACC1(p4.x) ACC1(p4.y) ACC1(p4.z) ACC1(p4.w)
  }
  for (; i < end; ++i) ACC1(packed[i]);
  __syncthreads();
  int node0 = k << BSHIFT;
  for (int tt = threadIdx.x; tt < BSIZE; tt += BTL) {
    int node = node0 + tt;
    if (node >= N) break;
    out[node] = fmaxf(0.0f, a[tt] * norm[node] + b6[0]);
  }
}

extern "C" void kernel_launch(void* const* d_in, const int* in_sizes, int n_in,
                              void* d_out, int out_size, void* d_ws, size_t ws_size,
                              hipStream_t stream) {
  const float* feat = (const float*)d_in[0];
  const float* norm = (const float*)d_in[1];
  const int* src = (const int*)d_in[2];
  const int* dst = (const int*)d_in[3];
  const float* W1 = (const float*)d_in[4];
  const float* b1 = (const float*)d_in[5];
  const float* W2 = (const float*)d_in[6];
  const float* b2 = (const float*)d_in[7];
  const float* W3 = (const float*)d_in[8];
  const float* b3 = (const float*)d_in[9];
  const float* W4 = (const float*)d_in[10];
  const float* b4 = (const float*)d_in[11];
  const float* W5 = (const float*)d_in[12];
  const float* b5 = (const float*)d_in[13];
  const float* W6 = (const float*)d_in[14];
  const float* b6 = (const float*)d_in[15];
  float* out = (float*)d_out;

  const int N = in_sizes[0];
  const int E = in_sizes[2];
  const int nbNode = (N + BT - 1) / BT;
  const int nBkt = (N + BSIZE - 1) >> BSHIFT;                 // 245
  const int chunk = (((E + NBLK - 1) / NBLK) + 3) & ~3;       // 16B-aligned chunks

  // Workspace: packed[E] | histB[M] | histT[M] | scanT[M] | partial[M/BT] |
  //            s0B[N]f | sA[4N]f | sA2[4N]f    (~103 MB)
  unsigned int* packed = (unsigned int*)d_ws;
  int* histB = (int*)(packed + (size_t)E);
  int* histT = histB + (size_t)M;
  int* scanT = histT + (size_t)M;
  int* partial = scanT + (size_t)M;
  float* s0B = (float*)(partial + M / BT);
  float* sA = s0B + (size_t)N;
  float* sA2 = sA + (size_t)4 * N;

  // --- Build (dst_bucket, src_superblock)-ordered edge list ---
  k_init<<<nbNode, BT, 0, stream>>>(feat, norm, s0B, N);
  k_phist<<<NBLK, BT, 0, stream>>>(src, dst, histB, E, chunk);
  {
    dim3 g1(NBINS / 64, NBLK / 64);  // histB[NBLK][NBINS] -> histT[NBINS][NBLK]
    k_transp<<<g1, BT, 0, stream>>>(histB, histT, NBLK, NBINS);
  }
  k_blockSum<<<M / BT, BT, 0, stream>>>(histT, partial, M);
  k_scanPartials<<<1, BT, 0, stream>>>(partial, M / BT);
  k_scanFinal<<<M / BT, BT, 0, stream>>>(histT, partial, M);
  {
    dim3 g2(NBLK / 64, NBINS / 64);  // histT[NBINS][NBLK] (scanned) -> scanT[NBLK][NBINS]
    k_transp<<<g2, BT, 0, stream>>>(histT, scanT, NBINS, NBLK);
  }
  k_pscatter<<<NBLK, BT, 0, stream>>>(src, dst, scanT, packed, E, chunk);

  // --- 6 fused layers ---
  k_layer1<<<nBkt, BTL, 0, stream>>>(scanT, packed, s0B, norm, W1, b1, sA, N);
  k_layer3<<<nBkt, BTL, 0, stream>>>(scanT, packed, sA, norm, W2, b2, sA2, N);
  k_layer3<<<nBkt, BTL, 0, stream>>>(scanT, packed, sA2, norm, W3, b3, sA, N);
  k_layer3<<<nBkt, BTL, 0, stream>>>(scanT, packed, sA, norm, W4, b4, sA2, N);
  k_layer5<<<nBkt, BTL, 0, stream>>>(scanT, packed, sA2, norm, W5, b5, W6, s0B, N);
  k_layer6<<<nBkt, BTL, 0, stream>>>(scanT, packed, s0B, norm, b6, out, N);
}